// Round 10
// baseline (366.362 us; speedup 1.0000x reference)
//
#include <hip/hip_runtime.h>
#include <math.h>

#define T_STEPS 256
#define Fdim 32
#define Udim 64
#define G4 256            // 4*U
#define OUT_STEPS 24
#define ROWS 16           // batch rows per group (= MFMA N)
#define GROUPS 2          // independent recurrences per block (latency hiding)
#define NBLK 128          // 4096 / (16*2)
#define NTHR 1024         // 16 waves = 2 groups x 8 waves, 4 waves/SIMD
#define HBS 72            // row stride in shorts (144 B, 36 dwords: measured-best layout)
#define CHUNK 16
#define NCHUNK 16         // 16 * 16 = 256 steps
#define LOG2E 1.4426950408889634f

typedef __attribute__((ext_vector_type(8))) short short8;   // 8 bf16 = 4 VGPR
typedef __attribute__((ext_vector_type(4))) float f32x4;

__device__ __forceinline__ short f2bf(float f) {
    union { float f; unsigned u; } v; v.f = f;
    unsigned r = v.u + 0x7FFFu + ((v.u >> 16) & 1u);   // RNE
    return (short)(r >> 16);
}
__device__ __forceinline__ float bf2f(short s) {
    union { unsigned u; float f; } v; v.u = ((unsigned)(unsigned short)s) << 16;
    return v.f;
}
__device__ __forceinline__ float frcp(float v) { return __builtin_amdgcn_rcpf(v); }
__device__ __forceinline__ float fexp2(float v) { return __builtin_amdgcn_exp2f(v); }

// packed f32x2 -> bf16x2 (RNE), 1 instruction
__device__ __forceinline__ unsigned pkbf(float lo, float hi) {
    unsigned r;
    asm("v_cvt_pk_bf16_f32 %0, %1, %2" : "=v"(r) : "v"(lo), "v"(hi));
    return r;
}

// LSTM cell with combined reciprocals (3 rcp instead of 5).
// Gates pre-scaled: i,f,o by log2e; g by 2*log2e.
__device__ __forceinline__ float cell_h(const f32x4 a, float& cst) {
    float A  = fexp2(-a[0]);
    float Bv = fexp2(a[2]);
    float rf = frcp(1.0f + fexp2(-a[1]));
    float ig = (Bv - 1.0f) * frcp((1.0f + A) * (1.0f + Bv));
    cst = fmaf(cst, rf, ig);
    float C  = fexp2(-a[3]);
    float D  = fexp2(2.0f * LOG2E * cst);
    return (D - 1.0f) * frcp((1.0f + C) * (1.0f + D));
}

// raw barrier: drains LDS (lgkmcnt) only -- NOT vmcnt -- so prefetched global
// loads stay in flight across the per-step barriers.
#define BAR() asm volatile("s_waitcnt lgkmcnt(0)\n\ts_barrier" ::: "memory")

#define MFMA __builtin_amdgcn_mfma_f32_16x16x32_bf16

// TWO independent 16-row LSTM recurrences per block (group = wave>>3). Each
// group is the proven v13 8-wave machine with private hb/xs; ONE block-wide
// barrier interval advances BOTH groups one step. The groups' dependent
// chains (ds_read -> MFMA -> trans) interleave on the shared SIMDs, filling
// the ~600 cy/step of exposed latency the single-group version pays.
// __launch_bounds__(1024, 4): 4 waves/SIMD -> VGPR cap 128 (v14's missing
// min-waves arg let the compiler pick 64 VGPRs and spill ~21 MB/dispatch).
__global__ __launch_bounds__(NTHR, 4)
void lstm_v15(const float* __restrict__ x,
              const float* __restrict__ W1, const float* __restrict__ U1, const float* __restrict__ b1,
              const float* __restrict__ W2, const float* __restrict__ U2, const float* __restrict__ b2,
              const float* __restrict__ Wd, const float* __restrict__ bd,
              float* __restrict__ out)
{
    __shared__ __align__(16) short hb[GROUPS][2][ROWS][HBS];     // bf16 h, ping-pong per group
    __shared__ __align__(16) short xs[GROUPS][CHUNK][ROWS][HBS]; // bf16 x chunk per group
    __shared__ __align__(16) float WdLf[Udim][Fdim];             // Wd staged fp32 (fold input)
    __shared__ __align__(16) unsigned short UeffB[Udim][G4];     // U2+Wd@W2, pre-scaled bf16
    __shared__ float beffL[G4];                                  // b2+bd@W2, fp32 unscaled

    const int tid = threadIdx.x;
    const int l   = tid & 63;
    const int w   = tid >> 6;         // wave 0..15
    const int g   = w >> 3;           // group 0/1
    const int w8  = w & 7;            // wave within group
    const int q   = l >> 4;
    const int m   = l & 15;
    const int brow_blk = blockIdx.x * (GROUPS * ROWS);
    const int brow_g   = brow_blk + g * ROWS;

    // ---- prefetch chunk 0 of x (32 rows x 16 steps x 32 feats = 4 float4/thread) ----
    const int f4 = tid & 7;           // float4 column 0..7
    const int tt = (tid >> 3) & 15;   // step within chunk
    const int xr = tid >> 7;          // base row 0..7; rows xr+8i
    float4 pf[4];
#pragma unroll
    for (int i = 0; i < 4; ++i)
        pf[i] = *(const float4*)&x[((size_t)(brow_blk + xr + 8 * i) * T_STEPS + tt) * Fdim + f4 * 4];

    // ---- stage LSTM1 weights as register-resident A-fragments (pre-scaled) ----
    short8 wa1[2][3];
    f32x4 bs1[2];
#pragma unroll
    for (int nt = 0; nt < 2; ++nt) {
        const int unit_a = w8 * 8 + (m >> 2) * 2 + nt; // A-row m -> (unit, gate)
        const int gate_a = m & 3;
        const int col = gate_a * 64 + unit_a;          // column in original [4U] layout
        const float sA = (gate_a == 2) ? 2.0f * LOG2E : LOG2E;
#pragma unroll
        for (int kt = 0; kt < 3; ++kt) {
            short8 fa;
#pragma unroll
            for (int j = 0; j < 8; ++j) {
                const int k = kt * 32 + q * 8 + j;
                fa[j] = f2bf(((k < Udim) ? U1[k * G4 + col] : W1[(k - Udim) * G4 + col]) * sA);
            }
            wa1[nt][kt] = fa;
        }
        const int unit_d = w8 * 8 + q * 2 + nt;
#pragma unroll
        for (int g2 = 0; g2 < 4; ++g2) {
            const float sD = (g2 == 2) ? 2.0f * LOG2E : LOG2E;
            bs1[nt][g2] = b1[g2 * 64 + unit_d] * sD;
        }
    }

    // ---- dense-output weights as hi/lo bf16 A-fragments (tile = wave 0 or 1 of group) ----
    short8 wdh[2], wdlo[2];
    f32x4 bdC;
    {
        const int wsel = (w8 < 2) ? w8 : 0;            // avoid OOB for unused waves
#pragma unroll
        for (int kt = 0; kt < 2; ++kt) {
            short8 fh, fl;
#pragma unroll
            for (int j = 0; j < 8; ++j) {
                const float v = Wd[(kt * 32 + q * 8 + j) * Fdim + 16 * wsel + m];
                const short hi = f2bf(v);
                fh[j] = hi;
                fl[j] = f2bf(v - bf2f(hi));
            }
            wdh[kt] = fh;
            wdlo[kt] = fl;
        }
#pragma unroll
        for (int g2 = 0; g2 < 4; ++g2) bdC[g2] = bd[16 * wsel + q * 4 + g2];
    }

    const int hw = w8 * 8 + q * 2;    // packed h write index (even)

    // ---- cooperative fold staging (each Ueff element computed once; v12 lesson) ----
    for (int idx = tid; idx < GROUPS * 2 * ROWS * HBS; idx += NTHR) ((short*)hb)[idx] = 0;
    for (int idx = tid; idx < Udim * Fdim; idx += NTHR) ((float*)WdLf)[idx] = Wd[idx];
    BAR();                            // WdLf (and hb zero) visible
    {
        const int colf = tid & 255;   // output column (coalesced)
        const int kq   = tid >> 8;    // k quarter: rows kq*16 .. kq*16+15
        float w2col[Fdim];            // W2[:, colf] -- coalesced, registers
#pragma unroll
        for (int f = 0; f < Fdim; ++f) w2col[f] = W2[f * G4 + colf];
        const float sAf = ((colf >> 6) == 2) ? 2.0f * LOG2E : LOG2E;
#pragma unroll
        for (int e = 0; e < 16; ++e) {
            const int k = kq * 16 + e;
            float v = U2[(size_t)k * G4 + colf];       // coalesced
#pragma unroll
            for (int f = 0; f < Fdim; ++f)
                v = fmaf(WdLf[k][f], w2col[f], v);     // LDS broadcast (wave-uniform)
            UeffB[k][colf] = (unsigned short)f2bf(v * sAf);
        }
        if (tid < G4) {               // beff = b2 + bd @ W2 (reuses w2col)
            float v = b2[colf];
#pragma unroll
            for (int f = 0; f < Fdim; ++f) v = fmaf(bd[f], w2col[f], v);
            beffL[colf] = v;
        }
    }
    BAR();                            // UeffB, beffL visible

    // ---- extract decode A-fragments from folded LDS ----
    short8 wa2[2][2];
    f32x4 bs2[2];
#pragma unroll
    for (int nt = 0; nt < 2; ++nt) {
        const int unit_a = w8 * 8 + (m >> 2) * 2 + nt;
        const int col = (m & 3) * 64 + unit_a;
#pragma unroll
        for (int kt = 0; kt < 2; ++kt) {
            short8 fb;
#pragma unroll
            for (int j = 0; j < 8; ++j)
                fb[j] = (short)UeffB[kt * 32 + q * 8 + j][col];
            wa2[nt][kt] = fb;
        }
        const int unit_d = w8 * 8 + q * 2 + nt;
#pragma unroll
        for (int g2 = 0; g2 < 4; ++g2) {
            const float sD = (g2 == 2) ? 2.0f * LOG2E : LOG2E;
            bs2[nt][g2] = beffL[g2 * 64 + unit_d] * sD;
        }
    }

    float cst[2] = {0.f, 0.f};

    // ================= warmup: 16 chunks x 16 steps, 1 raw barrier/step =================
    for (int c = 0; c < NCHUNK; ++c) {
        // convert prefetched chunk to bf16 and stage (row r -> group r>>4)
#pragma unroll
        for (int i = 0; i < 4; ++i) {
            const int r = xr + 8 * i;
            uint2 pk;
            pk.x = pkbf(pf[i].x, pf[i].y);
            pk.y = pkbf(pf[i].z, pf[i].w);
            *(uint2*)&xs[r >> 4][tt][r & 15][f4 * 4] = pk;
        }
        // issue next chunk's loads; in flight across all 16 step barriers
        if (c + 1 < NCHUNK) {
#pragma unroll
            for (int i = 0; i < 4; ++i)
                pf[i] = *(const float4*)&x[((size_t)(brow_blk + xr + 8 * i) * T_STEPS + ((c + 1) * CHUNK + tt)) * Fdim + f4 * 4];
        }
        BAR();                        // xs visible

        // two half-chunks: xf burst of 8 (not 16) keeps VGPR under the
        // 4-waves/SIMD 128 cliff; second burst overlaps step-7's compute
#pragma unroll
        for (int half = 0; half < 2; ++half) {
            short8 xf[8];
#pragma unroll
            for (int t = 0; t < 8; ++t)
                xf[t] = *(const short8*)&xs[g][half * 8 + t][m][q * 8];

#pragma unroll
            for (int t2 = 0; t2 < 8; ++t2) {
                const int p = t2 & 1; // global step parity = t2&1 (c*16, half*8 even)

                const short8 b0  = *(const short8*)&hb[g][p][m][q * 8];
                const short8 b1v = *(const short8*)&hb[g][p][m][32 + q * 8];

                // x-MFMAs first: register operands issue at barrier release,
                // covering the h-frag ds_read latency
                f32x4 a0 = MFMA(wa1[0][2], xf[t2], bs1[0], 0, 0, 0);
                f32x4 a1 = MFMA(wa1[1][2], xf[t2], bs1[1], 0, 0, 0);
                a0 = MFMA(wa1[0][0], b0, a0, 0, 0, 0);
                a1 = MFMA(wa1[1][0], b0, a1, 0, 0, 0);
                a0 = MFMA(wa1[0][1], b1v, a0, 0, 0, 0);
                a1 = MFMA(wa1[1][1], b1v, a1, 0, 0, 0);

                const float h0 = cell_h(a0, cst[0]);
                const float h1 = cell_h(a1, cst[1]);
                *(unsigned*)&hb[g][1 - p][m][hw] = pkbf(h0, h1);
                BAR();                // doubles as pre-stage barrier for next chunk
            }
        }
    }

    // ================= decode: 23 folded LSTM steps, 1 barrier/step, both groups =================
    int dp = 0;
    for (int s = 1; s < OUT_STEPS; ++s) {
        const short8 b0p = *(const short8*)&hb[g][dp][m][q * 8];
        const short8 b1p = *(const short8*)&hb[g][dp][m][32 + q * 8];

        f32x4 a0 = MFMA(wa2[0][0], b0p, bs2[0], 0, 0, 0);
        f32x4 a1 = MFMA(wa2[1][0], b0p, bs2[1], 0, 0, 0);
        a0 = MFMA(wa2[0][1], b1p, a0, 0, 0, 0);
        a1 = MFMA(wa2[1][1], b1p, a1, 0, 0, 0);

        const float h0 = cell_h(a0, cst[0]);
        const float h1 = cell_h(a1, cst[1]);
        *(unsigned*)&hb[g][1 - dp][m][hw] = pkbf(h0, h1);

        if (w8 < 2) {                 // fp32 pred(s-1) output, off the sync path
            f32x4 pz = MFMA(wdh[0], b0p, bdC, 0, 0, 0);
            pz = MFMA(wdh[1], b1p, pz, 0, 0, 0);
            pz = MFMA(wdlo[0], b0p, pz, 0, 0, 0);
            pz = MFMA(wdlo[1], b1p, pz, 0, 0, 0);
            *(f32x4*)&out[(size_t)(brow_g + m) * (OUT_STEPS * Fdim) + (s - 1) * Fdim + 16 * w8 + q * 4] = pz;
        }
        BAR();
        dp = 1 - dp;
    }
    // final pred(23) from h(23) in hb[g][dp]
    if (w8 < 2) {
        const short8 b0p = *(const short8*)&hb[g][dp][m][q * 8];
        const short8 b1p = *(const short8*)&hb[g][dp][m][32 + q * 8];
        f32x4 pz = MFMA(wdh[0], b0p, bdC, 0, 0, 0);
        pz = MFMA(wdh[1], b1p, pz, 0, 0, 0);
        pz = MFMA(wdlo[0], b0p, pz, 0, 0, 0);
        pz = MFMA(wdlo[1], b1p, pz, 0, 0, 0);
        *(f32x4*)&out[(size_t)(brow_g + m) * (OUT_STEPS * Fdim) + (OUT_STEPS - 1) * Fdim + 16 * w8 + q * 4] = pz;
    }
}

extern "C" void kernel_launch(void* const* d_in, const int* in_sizes, int n_in,
                              void* d_out, int out_size, void* d_ws, size_t ws_size,
                              hipStream_t stream) {
    (void)in_sizes; (void)n_in; (void)out_size; (void)d_ws; (void)ws_size;
    const float* x  = (const float*)d_in[0];
    const float* W1 = (const float*)d_in[1];
    const float* U1 = (const float*)d_in[2];
    const float* b1 = (const float*)d_in[3];
    const float* W2 = (const float*)d_in[4];
    const float* U2 = (const float*)d_in[5];
    const float* b2 = (const float*)d_in[6];
    const float* Wd = (const float*)d_in[7];
    const float* bd = (const float*)d_in[8];
    float* out = (float*)d_out;

    lstm_v15<<<dim3(NBLK), dim3(NTHR), 0, stream>>>(
        x, W1, U1, b1, W2, U2, b2, Wd, bd, out);
}

// Round 11
// 354.098 us; speedup vs baseline: 1.0346x; 1.0346x over previous
//
#include <hip/hip_runtime.h>
#include <math.h>

#define T_STEPS 256
#define Fdim 32
#define Udim 64
#define G4 256            // 4*U
#define OUT_STEPS 24
#define ROWS 16           // batch rows per group (= MFMA N)
#define GROUPS 2          // independent recurrences per block, interleaved IN-WAVE (ILP)
#define NBLK 128          // 4096 / 32
#define NTHR 512          // 8 waves, 2 waves/SIMD: the only shell proven spill-free at high VGPR
#define HBS 72            // row stride in shorts (144 B, 36 dwords: measured-best layout)
#define CHUNK 8
#define NCHUNK 32         // 32 * 8 = 256 steps
#define LOG2E 1.4426950408889634f

typedef __attribute__((ext_vector_type(8))) short short8;   // 8 bf16 = 4 VGPR
typedef __attribute__((ext_vector_type(4))) float f32x4;

__device__ __forceinline__ short f2bf(float f) {
    union { float f; unsigned u; } v; v.f = f;
    unsigned r = v.u + 0x7FFFu + ((v.u >> 16) & 1u);   // RNE
    return (short)(r >> 16);
}
__device__ __forceinline__ float bf2f(short s) {
    union { unsigned u; float f; } v; v.u = ((unsigned)(unsigned short)s) << 16;
    return v.f;
}
__device__ __forceinline__ float frcp(float v) { return __builtin_amdgcn_rcpf(v); }
__device__ __forceinline__ float fexp2(float v) { return __builtin_amdgcn_exp2f(v); }

// packed f32x2 -> bf16x2 (RNE), 1 instruction
__device__ __forceinline__ unsigned pkbf(float lo, float hi) {
    unsigned r;
    asm("v_cvt_pk_bf16_f32 %0, %1, %2" : "=v"(r) : "v"(lo), "v"(hi));
    return r;
}

// LSTM cell with combined reciprocals (3 rcp instead of 5).
// Gates pre-scaled: i,f,o by log2e; g by 2*log2e.
__device__ __forceinline__ float cell_h(const f32x4 a, float& cst) {
    float A  = fexp2(-a[0]);
    float Bv = fexp2(a[2]);
    float rf = frcp(1.0f + fexp2(-a[1]));
    float ig = (Bv - 1.0f) * frcp((1.0f + A) * (1.0f + Bv));
    cst = fmaf(cst, rf, ig);
    float C  = fexp2(-a[3]);
    float D  = fexp2(2.0f * LOG2E * cst);
    return (D - 1.0f) * frcp((1.0f + C) * (1.0f + D));
}

// raw barrier: drains LDS (lgkmcnt) only -- NOT vmcnt -- so prefetched global
// loads stay in flight across the per-step barriers.
#define BAR() asm volatile("s_waitcnt lgkmcnt(0)\n\ts_barrier" ::: "memory")

#define MFMA __builtin_amdgcn_mfma_f32_16x16x32_bf16

// TWO independent 16-row recurrences (groups) per 512-thread block, both
// carried by EVERY wave: per interval a wave issues 12 MFMAs + 4 cells
// (2 tiles x 2 groups). The groups' dependent chains interleave at the
// instruction level inside the wave -- group B's register-operand MFMAs and
// trans ops fill group A's ds_read/MFMA latency (v8 showed lockstep waves
// DON'T provide this; ILP does it deterministically).
// Per group: wave w owns gate-row tiles 2w, 2w+1; lane (q,m) owns cells
// (units w*8+q*2, +1; batch row m).
__global__ __launch_bounds__(NTHR, 2)
void lstm_v16(const float* __restrict__ x,
              const float* __restrict__ W1, const float* __restrict__ U1, const float* __restrict__ b1,
              const float* __restrict__ W2, const float* __restrict__ U2, const float* __restrict__ b2,
              const float* __restrict__ Wd, const float* __restrict__ bd,
              float* __restrict__ out)
{
    __shared__ __align__(16) short hb[GROUPS][2][ROWS][HBS];     // bf16 h, ping-pong per group
    __shared__ __align__(16) short xs[GROUPS][CHUNK][ROWS][HBS]; // bf16 x chunk per group
    __shared__ __align__(16) float WdLf[Udim][Fdim];             // Wd staged fp32 (fold input)
    __shared__ __align__(16) unsigned short UeffB[Udim][G4];     // U2+Wd@W2, pre-scaled bf16
    __shared__ float beffL[G4];                                  // b2+bd@W2, fp32 unscaled

    const int tid = threadIdx.x;
    const int l   = tid & 63;
    const int w   = tid >> 6;         // wave 0..7
    const int q   = l >> 4;
    const int m   = l & 15;
    const int brow_blk = blockIdx.x * (GROUPS * ROWS);

    // ---- prefetch chunk 0 of x (32 rows x 8 steps x 32 feats = 4 float4/thread) ----
    const int f4   = tid & 7;         // float4 column 0..7
    const int sstp = (tid >> 3) & 7;  // step within chunk
    const int srow = tid >> 6;        // base row 0..7; rows srow+8i, i=0..3
    float4 pf[4];
#pragma unroll
    for (int i = 0; i < 4; ++i)
        pf[i] = *(const float4*)&x[((size_t)(brow_blk + srow + 8 * i) * T_STEPS + sstp) * Fdim + f4 * 4];

    // ---- stage LSTM1 weights as register-resident A-fragments (pre-scaled) ----
    short8 wa1[2][3];
    f32x4 bs1[2];
#pragma unroll
    for (int nt = 0; nt < 2; ++nt) {
        const int unit_a = w * 8 + (m >> 2) * 2 + nt;  // A-row m -> (unit, gate)
        const int gate_a = m & 3;
        const int col = gate_a * 64 + unit_a;          // column in original [4U] layout
        const float sA = (gate_a == 2) ? 2.0f * LOG2E : LOG2E;
#pragma unroll
        for (int kt = 0; kt < 3; ++kt) {
            short8 fa;
#pragma unroll
            for (int j = 0; j < 8; ++j) {
                const int k = kt * 32 + q * 8 + j;
                fa[j] = f2bf(((k < Udim) ? U1[k * G4 + col] : W1[(k - Udim) * G4 + col]) * sA);
            }
            wa1[nt][kt] = fa;
        }
        const int unit_d = w * 8 + q * 2 + nt;
#pragma unroll
        for (int g2 = 0; g2 < 4; ++g2) {
            const float sD = (g2 == 2) ? 2.0f * LOG2E : LOG2E;
            bs1[nt][g2] = b1[g2 * 64 + unit_d] * sD;
        }
    }

    // ---- dense-output weights: waves 0,1 -> group A tiles 0,1; waves 2,3 -> group B ----
    short8 wdh[2], wdlo[2];
    f32x4 bdC;
    const int gd   = (w >> 1) & 1;    // dense group (valid for w<4)
    const int wsel = w & 1;           // dense tile within group
    {
#pragma unroll
        for (int kt = 0; kt < 2; ++kt) {
            short8 fh, fl;
#pragma unroll
            for (int j = 0; j < 8; ++j) {
                const float v = Wd[(kt * 32 + q * 8 + j) * Fdim + 16 * wsel + m];
                const short hi = f2bf(v);
                fh[j] = hi;
                fl[j] = f2bf(v - bf2f(hi));
            }
            wdh[kt] = fh;
            wdlo[kt] = fl;
        }
#pragma unroll
        for (int g2 = 0; g2 < 4; ++g2) bdC[g2] = bd[16 * wsel + q * 4 + g2];
    }

    const int hw = w * 8 + q * 2;     // packed h write index (even)

    // ---- cooperative fold staging (each Ueff element computed once; v12 lesson) ----
    for (int idx = tid; idx < GROUPS * 2 * ROWS * HBS; idx += NTHR) ((short*)hb)[idx] = 0;
    for (int idx = tid; idx < Udim * Fdim; idx += NTHR) ((float*)WdLf)[idx] = Wd[idx];
    BAR();                            // WdLf (and hb zero) visible
    {
        const int colf = tid & 255;   // output column (coalesced)
        const int kh   = tid >> 8;    // k half: rows kh*32 .. kh*32+31
        float w2col[Fdim];            // W2[:, colf] -- coalesced, registers
#pragma unroll
        for (int f = 0; f < Fdim; ++f) w2col[f] = W2[f * G4 + colf];
        const float sAf = ((colf >> 6) == 2) ? 2.0f * LOG2E : LOG2E;
#pragma unroll
        for (int e = 0; e < 32; ++e) {
            const int k = kh * 32 + e;
            float v = U2[(size_t)k * G4 + colf];       // coalesced
#pragma unroll
            for (int f = 0; f < Fdim; ++f)
                v = fmaf(WdLf[k][f], w2col[f], v);     // LDS broadcast (wave-uniform)
            UeffB[k][colf] = (unsigned short)f2bf(v * sAf);
        }
        if (tid < G4) {               // beff = b2 + bd @ W2 (reuses w2col)
            float v = b2[colf];
#pragma unroll
            for (int f = 0; f < Fdim; ++f) v = fmaf(bd[f], w2col[f], v);
            beffL[colf] = v;
        }
    }
    BAR();                            // UeffB, beffL visible

    // ---- extract decode A-fragments from folded LDS ----
    short8 wa2[2][2];
    f32x4 bs2[2];
#pragma unroll
    for (int nt = 0; nt < 2; ++nt) {
        const int unit_a = w * 8 + (m >> 2) * 2 + nt;
        const int col = (m & 3) * 64 + unit_a;
#pragma unroll
        for (int kt = 0; kt < 2; ++kt) {
            short8 fb;
#pragma unroll
            for (int j = 0; j < 8; ++j)
                fb[j] = (short)UeffB[kt * 32 + q * 8 + j][col];
            wa2[nt][kt] = fb;
        }
        const int unit_d = w * 8 + q * 2 + nt;
#pragma unroll
        for (int g2 = 0; g2 < 4; ++g2) {
            const float sD = (g2 == 2) ? 2.0f * LOG2E : LOG2E;
            bs2[nt][g2] = beffL[g2 * 64 + unit_d] * sD;
        }
    }

    float cstA[2] = {0.f, 0.f}, cstB[2] = {0.f, 0.f};

    // ================= warmup: 32 chunks x 8 steps, 1 raw barrier/step =================
    for (int c = 0; c < NCHUNK; ++c) {
        // convert prefetched chunk to bf16 and stage (row r -> group r>>4)
#pragma unroll
        for (int i = 0; i < 4; ++i) {
            const int r = srow + 8 * i;
            uint2 pk;
            pk.x = pkbf(pf[i].x, pf[i].y);
            pk.y = pkbf(pf[i].z, pf[i].w);
            *(uint2*)&xs[r >> 4][sstp][r & 15][f4 * 4] = pk;
        }
        // issue next chunk's loads; in flight across all 8 step barriers
        if (c + 1 < NCHUNK) {
#pragma unroll
            for (int i = 0; i < 4; ++i)
                pf[i] = *(const float4*)&x[((size_t)(brow_blk + srow + 8 * i) * T_STEPS + ((c + 1) * CHUNK + sstp)) * Fdim + f4 * 4];
        }
        BAR();                        // xs visible

        // burst-read both groups' x B-frags (off the step critical path)
        short8 xfA[CHUNK], xfB[CHUNK];
#pragma unroll
        for (int t = 0; t < CHUNK; ++t) {
            xfA[t] = *(const short8*)&xs[0][t][m][q * 8];
            xfB[t] = *(const short8*)&xs[1][t][m][q * 8];
        }

#pragma unroll
        for (int t2 = 0; t2 < CHUNK; ++t2) {
            const int p = t2 & 1;     // chunk length even -> parity continues

            const short8 b0A = *(const short8*)&hb[0][p][m][q * 8];
            const short8 b1A = *(const short8*)&hb[0][p][m][32 + q * 8];
            const short8 b0B = *(const short8*)&hb[1][p][m][q * 8];
            const short8 b1B = *(const short8*)&hb[1][p][m][32 + q * 8];

            // 4 register-operand x-MFMAs issue at barrier release, covering
            // all four h-frag ds_reads
            f32x4 a0A = MFMA(wa1[0][2], xfA[t2], bs1[0], 0, 0, 0);
            f32x4 a1A = MFMA(wa1[1][2], xfA[t2], bs1[1], 0, 0, 0);
            f32x4 a0B = MFMA(wa1[0][2], xfB[t2], bs1[0], 0, 0, 0);
            f32x4 a1B = MFMA(wa1[1][2], xfB[t2], bs1[1], 0, 0, 0);
            a0A = MFMA(wa1[0][0], b0A, a0A, 0, 0, 0);
            a1A = MFMA(wa1[1][0], b0A, a1A, 0, 0, 0);
            a0B = MFMA(wa1[0][0], b0B, a0B, 0, 0, 0);
            a1B = MFMA(wa1[1][0], b0B, a1B, 0, 0, 0);
            a0A = MFMA(wa1[0][1], b1A, a0A, 0, 0, 0);
            a1A = MFMA(wa1[1][1], b1A, a1A, 0, 0, 0);
            a0B = MFMA(wa1[0][1], b1B, a0B, 0, 0, 0);
            a1B = MFMA(wa1[1][1], b1B, a1B, 0, 0, 0);

            // group A's cells run while group B's MFMA chain finishes, and
            // vice versa -- the two chains fill each other's stalls
            const float hA0 = cell_h(a0A, cstA[0]);
            const float hA1 = cell_h(a1A, cstA[1]);
            const float hB0 = cell_h(a0B, cstB[0]);
            const float hB1 = cell_h(a1B, cstB[1]);
            *(unsigned*)&hb[0][1 - p][m][hw] = pkbf(hA0, hA1);
            *(unsigned*)&hb[1][1 - p][m][hw] = pkbf(hB0, hB1);
            BAR();                    // doubles as pre-stage barrier for next chunk
        }
    }

    // ================= decode: 23 folded LSTM steps, 1 barrier/step, both groups =================
    int dp = 0;
    for (int s = 1; s < OUT_STEPS; ++s) {
        const short8 b0A = *(const short8*)&hb[0][dp][m][q * 8];
        const short8 b1A = *(const short8*)&hb[0][dp][m][32 + q * 8];
        const short8 b0B = *(const short8*)&hb[1][dp][m][q * 8];
        const short8 b1B = *(const short8*)&hb[1][dp][m][32 + q * 8];

        f32x4 a0A = MFMA(wa2[0][0], b0A, bs2[0], 0, 0, 0);
        f32x4 a1A = MFMA(wa2[1][0], b0A, bs2[1], 0, 0, 0);
        f32x4 a0B = MFMA(wa2[0][0], b0B, bs2[0], 0, 0, 0);
        f32x4 a1B = MFMA(wa2[1][0], b0B, bs2[1], 0, 0, 0);
        a0A = MFMA(wa2[0][1], b1A, a0A, 0, 0, 0);
        a1A = MFMA(wa2[1][1], b1A, a1A, 0, 0, 0);
        a0B = MFMA(wa2[0][1], b1B, a0B, 0, 0, 0);
        a1B = MFMA(wa2[1][1], b1B, a1B, 0, 0, 0);

        const float hA0 = cell_h(a0A, cstA[0]);
        const float hA1 = cell_h(a1A, cstA[1]);
        const float hB0 = cell_h(a0B, cstB[0]);
        const float hB1 = cell_h(a1B, cstB[1]);
        *(unsigned*)&hb[0][1 - dp][m][hw] = pkbf(hA0, hA1);
        *(unsigned*)&hb[1][1 - dp][m][hw] = pkbf(hB0, hB1);

        if (w < 4) {                  // fp32 pred(s-1): waves 0,1 -> A; 2,3 -> B
            const short8 d0 = gd ? b0B : b0A;
            const short8 d1 = gd ? b1B : b1A;
            f32x4 pz = MFMA(wdh[0], d0, bdC, 0, 0, 0);
            pz = MFMA(wdh[1], d1, pz, 0, 0, 0);
            pz = MFMA(wdlo[0], d0, pz, 0, 0, 0);
            pz = MFMA(wdlo[1], d1, pz, 0, 0, 0);
            *(f32x4*)&out[(size_t)(brow_blk + gd * ROWS + m) * (OUT_STEPS * Fdim) + (s - 1) * Fdim + 16 * wsel + q * 4] = pz;
        }
        BAR();
        dp = 1 - dp;
    }
    // final pred(23) from h(23) in hb[*][dp]
    if (w < 4) {
        const short8 d0 = *(const short8*)&hb[gd][dp][m][q * 8];
        const short8 d1 = *(const short8*)&hb[gd][dp][m][32 + q * 8];
        f32x4 pz = MFMA(wdh[0], d0, bdC, 0, 0, 0);
        pz = MFMA(wdh[1], d1, pz, 0, 0, 0);
        pz = MFMA(wdlo[0], d0, pz, 0, 0, 0);
        pz = MFMA(wdlo[1], d1, pz, 0, 0, 0);
        *(f32x4*)&out[(size_t)(brow_blk + gd * ROWS + m) * (OUT_STEPS * Fdim) + (OUT_STEPS - 1) * Fdim + 16 * wsel + q * 4] = pz;
    }
}

extern "C" void kernel_launch(void* const* d_in, const int* in_sizes, int n_in,
                              void* d_out, int out_size, void* d_ws, size_t ws_size,
                              hipStream_t stream) {
    (void)in_sizes; (void)n_in; (void)out_size; (void)d_ws; (void)ws_size;
    const float* x  = (const float*)d_in[0];
    const float* W1 = (const float*)d_in[1];
    const float* U1 = (const float*)d_in[2];
    const float* b1 = (const float*)d_in[3];
    const float* W2 = (const float*)d_in[4];
    const float* U2 = (const float*)d_in[5];
    const float* b2 = (const float*)d_in[6];
    const float* Wd = (const float*)d_in[7];
    const float* bd = (const float*)d_in[8];
    float* out = (float*)d_out;

    lstm_v16<<<dim3(NBLK), dim3(NTHR), 0, stream>>>(
        x, W1, U1, b1, W2, U2, b2, Wd, bd, out);
}

// Round 12
// 269.184 us; speedup vs baseline: 1.3610x; 1.3155x over previous
//
#include <hip/hip_runtime.h>
#include <math.h>

#define T_STEPS 256
#define Fdim 32
#define Udim 64
#define G4 256            // 4*U
#define OUT_STEPS 24
#define ROWS 16           // batch rows per block (= MFMA N)
#define NBLK 256          // 4096 / 16 -- full-chip partition (v16: 128 blocks wastes half the CUs)
#define NTHR 512          // 8 waves, 2 waves/SIMD: measured-best (v6/v8/v9/v16 sweep)
#define HBS 72            // row stride in shorts (144 B, 36 dwords: measured-best layout)
#define CHUNK 16
#define NCHUNK 16         // 16 * 16 = 256 steps
#define LOG2E 1.4426950408889634f

typedef __attribute__((ext_vector_type(8))) short short8;   // 8 bf16 = 4 VGPR
typedef __attribute__((ext_vector_type(4))) float f32x4;
typedef __attribute__((ext_vector_type(2))) float f32x2;    // packed: v_pk_*_f32

__device__ __forceinline__ short f2bf(float f) {
    union { float f; unsigned u; } v; v.f = f;
    unsigned r = v.u + 0x7FFFu + ((v.u >> 16) & 1u);   // RNE
    return (short)(r >> 16);
}
__device__ __forceinline__ float bf2f(short s) {
    union { unsigned u; float f; } v; v.u = ((unsigned)(unsigned short)s) << 16;
    return v.f;
}
__device__ __forceinline__ float frcp(float v) { return __builtin_amdgcn_rcpf(v); }
__device__ __forceinline__ float fexp2(float v) { return __builtin_amdgcn_exp2f(v); }

// packed f32x2 -> bf16x2 (RNE), 1 instruction
__device__ __forceinline__ unsigned pkbf(float lo, float hi) {
    unsigned r;
    asm("v_cvt_pk_bf16_f32 %0, %1, %2" : "=v"(r) : "v"(lo), "v"(hi));
    return r;
}

__device__ __forceinline__ f32x2 exp2v(f32x2 v) {
    f32x2 r; r[0] = fexp2(v[0]); r[1] = fexp2(v[1]); return r;
}
__device__ __forceinline__ f32x2 rcpv(f32x2 v) {
    f32x2 r; r[0] = frcp(v[0]); r[1] = frcp(v[1]); return r;
}

// Dual-cell LSTM update, packed f32x2 across the two cells, 7 trans/cell:
// gates pre-scaled (i,f,o by log2e; g by 2*log2e).
//   cst' = cst/(1+F) + (B-1)/P          P=(1+A)(1+B), A=2^-si, B=2^sg, F=2^-sf
//        = [cst*P + (B-1)(1+F)] * rcp(P*(1+F))      -- ONE rcp (was two)
//   h    = (D-1) * rcp((1+C)(1+D))      C=2^-so, D=2^(2*log2e*cst')
// Scalar VALU pairs fuse to v_pk_{add,mul,fma}_f32; exp2/rcp stay scalar.
__device__ __forceinline__ f32x2 cell2(const f32x4 a0, const f32x4 a1, f32x2& cst) {
    const f32x2 si = {a0[0], a1[0]};
    const f32x2 sf = {a0[1], a1[1]};
    const f32x2 sg = {a0[2], a1[2]};
    const f32x2 so = {a0[3], a1[3]};
    const f32x2 A = exp2v(-si);
    const f32x2 B = exp2v(sg);
    const f32x2 F = exp2v(-sf);
    const f32x2 P  = (1.0f + A) * (1.0f + B);
    const f32x2 F1 = 1.0f + F;
    const f32x2 num = cst * P + (B - 1.0f) * F1;
    cst = num * rcpv(P * F1);
    const f32x2 C = exp2v(-so);
    const f32x2 D = exp2v((2.0f * LOG2E) * cst);
    return (D - 1.0f) * rcpv((1.0f + C) * (1.0f + D));
}

// raw barrier: drains LDS (lgkmcnt) only -- NOT vmcnt -- so prefetched global
// loads stay in flight across the per-step barriers.
#define BAR() asm volatile("s_waitcnt lgkmcnt(0)\n\ts_barrier" ::: "memory")

#define MFMA __builtin_amdgcn_mfma_f32_16x16x32_bf16

// z^T = Wt[256 gate-rows x 96] @ hx^T[96 x 16 rows], tile t covers gate-rows t*16..t*16+15.
// Wave w (0..7) owns tiles 2w, 2w+1 -> lane (q,m) owns cells (units w*8+q*2, w*8+q*2+1; row m)
// A-frag: lane l holds A[m=l&15][k=(l>>4)*8+j] (static pre-scaled weights in VGPRs)
// B-frag: lane l holds B[k=(l>>4)*8+j][n=l&15] (hb reads; x frags register-resident per chunk)
// C/D:    lane l holds D[row=q*4+reg][col=m]   (4 gates of one cell per lane)
// Decode folded: Ueff = U2 + Wd@W2, beff = b2 + bd@W2 (cooperative fp32 fold);
// fp32 pred via hi/lo-split Wd MFMAs on waves 0,1, off the sync path.
__global__ __launch_bounds__(NTHR, 2)
void lstm_v17(const float* __restrict__ x,
              const float* __restrict__ W1, const float* __restrict__ U1, const float* __restrict__ b1,
              const float* __restrict__ W2, const float* __restrict__ U2, const float* __restrict__ b2,
              const float* __restrict__ Wd, const float* __restrict__ bd,
              float* __restrict__ out)
{
    __shared__ __align__(16) short hb[2][ROWS][HBS];     // bf16 h, ping-pong
    __shared__ __align__(16) short xs[CHUNK][ROWS][HBS]; // bf16 x chunk
    __shared__ __align__(16) float WdLf[Udim][Fdim];     // Wd staged fp32 (fold input)
    __shared__ __align__(16) unsigned short UeffB[Udim][G4]; // folded U2+Wd@W2, pre-scaled bf16
    __shared__ float beffL[G4];                          // folded b2+bd@W2, fp32 unscaled

    const int tid = threadIdx.x;
    const int l   = tid & 63;
    const int w   = tid >> 6;         // wave 0..7
    const int q   = l >> 4;
    const int m   = l & 15;
    const int brow = blockIdx.x * ROWS;

    // ---- prefetch chunk 0 of x into registers (hide HBM latency under staging) ----
    const int f4  = tid & 7;          // float4 column 0..7
    const int tt  = (tid >> 3) & 15;  // step within chunk
    const int xr0 = tid >> 7;         // base row 0..3; rows xr0+4i
    float4 pf[4];
#pragma unroll
    for (int i = 0; i < 4; ++i)
        pf[i] = *(const float4*)&x[((size_t)(brow + xr0 + 4 * i) * T_STEPS + tt) * Fdim + f4 * 4];

    // ---- stage LSTM1 weights as register-resident A-fragments (pre-scaled) ----
    short8 wa1[2][3];
    f32x4 bs1[2];
#pragma unroll
    for (int nt = 0; nt < 2; ++nt) {
        const int unit_a = w * 8 + (m >> 2) * 2 + nt;  // A-row m -> (unit, gate)
        const int gate_a = m & 3;
        const int col = gate_a * 64 + unit_a;          // column in original [4U] layout
        const float sA = (gate_a == 2) ? 2.0f * LOG2E : LOG2E;
#pragma unroll
        for (int kt = 0; kt < 3; ++kt) {
            short8 fa;
#pragma unroll
            for (int j = 0; j < 8; ++j) {
                const int k = kt * 32 + q * 8 + j;
                fa[j] = f2bf(((k < Udim) ? U1[k * G4 + col] : W1[(k - Udim) * G4 + col]) * sA);
            }
            wa1[nt][kt] = fa;
        }
        const int unit_d = w * 8 + q * 2 + nt;
#pragma unroll
        for (int g = 0; g < 4; ++g) {
            const float sD = (g == 2) ? 2.0f * LOG2E : LOG2E;
            bs1[nt][g] = b1[g * 64 + unit_d] * sD;
        }
    }

    // ---- dense-output weights as hi/lo bf16 A-fragments (tile = wave 0 or 1) ----
    short8 wdh[2], wdlo[2];
    f32x4 bdC;
    {
        const int wsel = (w < 2) ? w : 0;              // avoid OOB for unused waves
#pragma unroll
        for (int kt = 0; kt < 2; ++kt) {
            short8 fh, fl;
#pragma unroll
            for (int j = 0; j < 8; ++j) {
                const float v = Wd[(kt * 32 + q * 8 + j) * Fdim + 16 * wsel + m];
                const short hi = f2bf(v);
                fh[j] = hi;
                fl[j] = f2bf(v - bf2f(hi));
            }
            wdh[kt] = fh;
            wdlo[kt] = fl;
        }
#pragma unroll
        for (int g = 0; g < 4; ++g) bdC[g] = bd[16 * wsel + q * 4 + g];
    }

    const int hw = w * 8 + q * 2;     // packed h write index (even)

    // ---- cooperative fold staging (each Ueff element computed once; v12 lesson) ----
    for (int idx = tid; idx < 2 * ROWS * HBS; idx += NTHR) ((short*)hb)[idx] = 0;
    for (int idx = tid; idx < Udim * Fdim; idx += NTHR) ((float*)WdLf)[idx] = Wd[idx];
    BAR();                            // WdLf (and hb zero) visible
    {
        const int colf = tid & 255;   // output column (coalesced)
        const int kh   = tid >> 8;    // k half: rows kh*32 .. kh*32+31
        float w2col[Fdim];            // W2[:, colf] -- coalesced loads, registers
#pragma unroll
        for (int f = 0; f < Fdim; ++f) w2col[f] = W2[f * G4 + colf];
        const float sAf = ((colf >> 6) == 2) ? 2.0f * LOG2E : LOG2E;
#pragma unroll
        for (int e = 0; e < 32; ++e) {
            const int k = kh * 32 + e;
            float v = U2[(size_t)k * G4 + colf];       // coalesced
#pragma unroll
            for (int f = 0; f < Fdim; ++f)
                v = fmaf(WdLf[k][f], w2col[f], v);     // LDS broadcast (wave-uniform)
            UeffB[k][colf] = (unsigned short)f2bf(v * sAf);
        }
        if (tid < G4) {               // beff = b2 + bd @ W2 (reuses w2col)
            float v = b2[colf];
#pragma unroll
            for (int f = 0; f < Fdim; ++f) v = fmaf(bd[f], w2col[f], v);
            beffL[colf] = v;
        }
    }
    BAR();                            // UeffB, beffL visible

    // ---- extract decode A-fragments from folded LDS ----
    short8 wa2[2][2];
    f32x4 bs2[2];
#pragma unroll
    for (int nt = 0; nt < 2; ++nt) {
        const int unit_a = w * 8 + (m >> 2) * 2 + nt;
        const int col = (m & 3) * 64 + unit_a;
#pragma unroll
        for (int kt = 0; kt < 2; ++kt) {
            short8 fb;
#pragma unroll
            for (int j = 0; j < 8; ++j)
                fb[j] = (short)UeffB[kt * 32 + q * 8 + j][col];
            wa2[nt][kt] = fb;
        }
        const int unit_d = w * 8 + q * 2 + nt;
#pragma unroll
        for (int g = 0; g < 4; ++g) {
            const float sD = (g == 2) ? 2.0f * LOG2E : LOG2E;
            bs2[nt][g] = beffL[g * 64 + unit_d] * sD;
        }
    }

    f32x2 cst = {0.f, 0.f};

    // ================= warmup: 16 chunks x 16 steps, 1 raw barrier/step =================
    for (int c = 0; c < NCHUNK; ++c) {
        // convert prefetched chunk to bf16 and stage
#pragma unroll
        for (int i = 0; i < 4; ++i) {
            uint2 pk;
            pk.x = pkbf(pf[i].x, pf[i].y);
            pk.y = pkbf(pf[i].z, pf[i].w);
            *(uint2*)&xs[tt][xr0 + 4 * i][f4 * 4] = pk;
        }
        // issue next chunk's loads; they stay in flight across all 16 step barriers
        if (c + 1 < NCHUNK) {
#pragma unroll
            for (int i = 0; i < 4; ++i)
                pf[i] = *(const float4*)&x[((size_t)(brow + xr0 + 4 * i) * T_STEPS + ((c + 1) * CHUNK + tt)) * Fdim + f4 * 4];
        }
        BAR();                        // xs visible

        // burst-read the chunk's x B-frags into registers (off the step critical path)
        short8 xf[CHUNK];
#pragma unroll
        for (int t = 0; t < CHUNK; ++t)
            xf[t] = *(const short8*)&xs[t][m][q * 8];

#pragma unroll
        for (int t2 = 0; t2 < CHUNK; ++t2) {
            const int p = t2 & 1;     // c*16 even -> parity continues across chunks

            const short8 b0  = *(const short8*)&hb[p][m][q * 8];
            const short8 b1v = *(const short8*)&hb[p][m][32 + q * 8];

            // x-MFMAs first: operands already in regs -> issue at barrier release,
            // covering the h-frag ds_read latency
            f32x4 a0 = MFMA(wa1[0][2], xf[t2], bs1[0], 0, 0, 0);
            f32x4 a1 = MFMA(wa1[1][2], xf[t2], bs1[1], 0, 0, 0);
            a0 = MFMA(wa1[0][0], b0, a0, 0, 0, 0);
            a1 = MFMA(wa1[1][0], b0, a1, 0, 0, 0);
            a0 = MFMA(wa1[0][1], b1v, a0, 0, 0, 0);
            a1 = MFMA(wa1[1][1], b1v, a1, 0, 0, 0);

            const f32x2 h = cell2(a0, a1, cst);
            *(unsigned*)&hb[1 - p][m][hw] = pkbf(h[0], h[1]);
            BAR();                    // doubles as pre-stage barrier for next chunk
        }
    }

    // ================= decode: 23 folded LSTM steps, 1 barrier/step =================
    // h(final warmup) in hb[0]. Iteration s: read h(s-1), compute h(s) via
    // Ueff/beff, and emit pred(s-1) = h(s-1)@Wd + bd (waves 0,1; off sync path).
    int dp = 0;
    for (int s = 1; s < OUT_STEPS; ++s) {
        const short8 b0p = *(const short8*)&hb[dp][m][q * 8];
        const short8 b1p = *(const short8*)&hb[dp][m][32 + q * 8];

        f32x4 a0 = MFMA(wa2[0][0], b0p, bs2[0], 0, 0, 0);
        f32x4 a1 = MFMA(wa2[1][0], b0p, bs2[1], 0, 0, 0);
        a0 = MFMA(wa2[0][1], b1p, a0, 0, 0, 0);
        a1 = MFMA(wa2[1][1], b1p, a1, 0, 0, 0);

        const f32x2 h = cell2(a0, a1, cst);
        *(unsigned*)&hb[1 - dp][m][hw] = pkbf(h[0], h[1]);

        if (w < 2) {                  // fp32 pred output
            f32x4 pz = MFMA(wdh[0], b0p, bdC, 0, 0, 0);
            pz = MFMA(wdh[1], b1p, pz, 0, 0, 0);
            pz = MFMA(wdlo[0], b0p, pz, 0, 0, 0);
            pz = MFMA(wdlo[1], b1p, pz, 0, 0, 0);
            *(f32x4*)&out[(size_t)(brow + m) * (OUT_STEPS * Fdim) + (s - 1) * Fdim + 16 * w + q * 4] = pz;
        }
        BAR();
        dp = 1 - dp;
    }
    // final pred(23) from h(23) in hb[dp]
    if (w < 2) {
        const short8 b0p = *(const short8*)&hb[dp][m][q * 8];
        const short8 b1p = *(const short8*)&hb[dp][m][32 + q * 8];
        f32x4 pz = MFMA(wdh[0], b0p, bdC, 0, 0, 0);
        pz = MFMA(wdh[1], b1p, pz, 0, 0, 0);
        pz = MFMA(wdlo[0], b0p, pz, 0, 0, 0);
        pz = MFMA(wdlo[1], b1p, pz, 0, 0, 0);
        *(f32x4*)&out[(size_t)(brow + m) * (OUT_STEPS * Fdim) + (OUT_STEPS - 1) * Fdim + 16 * w + q * 4] = pz;
    }
}

extern "C" void kernel_launch(void* const* d_in, const int* in_sizes, int n_in,
                              void* d_out, int out_size, void* d_ws, size_t ws_size,
                              hipStream_t stream) {
    (void)in_sizes; (void)n_in; (void)out_size; (void)d_ws; (void)ws_size;
    const float* x  = (const float*)d_in[0];
    const float* W1 = (const float*)d_in[1];
    const float* U1 = (const float*)d_in[2];
    const float* b1 = (const float*)d_in[3];
    const float* W2 = (const float*)d_in[4];
    const float* U2 = (const float*)d_in[5];
    const float* b2 = (const float*)d_in[6];
    const float* Wd = (const float*)d_in[7];
    const float* bd = (const float*)d_in[8];
    float* out = (float*)d_out;

    lstm_v17<<<dim3(NBLK), dim3(NTHR), 0, stream>>>(
        x, W1, U1, b1, W2, U2, b2, Wd, bd, out);
}